// Round 6
// baseline (1149.318 us; speedup 1.0000x reference)
//
#include <hip/hip_runtime.h>
#include <cstdint>

// PQ ADC search, MI355X round 6.
// Coarse scan m-outer: per-m 8KB u8 table column double-buffered through LDS
// (no global gathers -> no L1-miss-queue bound); codes staged in LDS.
// Threshold computed in quantized domain (sampled 12th qsum + 64 slack,
// provably conservative). Exact fp32 refine (reference summation order,
// bit-identical) -> bitonic top-64.

#define BQ 32
#define MSUB 64
#define KSUB 256
#define KOUT 64
#define NSAMP 8192
#define TAU_RANK 12        // 12th smallest sampled qsum; P(miss top-64) ~ 1e-13
#define CAP 8192
#define NSORT 8192
#define ROWS 512           // rows per coarse block

__device__ __forceinline__ unsigned pack4(int4 a) {
    return (unsigned)(a.x & 255) | ((unsigned)(a.y & 255) << 8) |
           ((unsigned)(a.z & 255) << 16) | ((unsigned)(a.w & 255) << 24);
}

// packed-u16 accumulate: aL += (b0, b2), aH += (b1, b3)
__device__ __forceinline__ void acc8(unsigned v, unsigned& aL, unsigned& aH) {
#if defined(__has_builtin) && __has_builtin(__builtin_amdgcn_perm)
    aL += __builtin_amdgcn_perm(0u, v, 0x0C020C00u);
    aH += __builtin_amdgcn_perm(0u, v, 0x0C030C01u);
#else
    aL += v & 0x00FF00FFu;
    aH += (v >> 8) & 0x00FF00FFu;
#endif
}

// ---------------- K1: fp32 distance table, layout table[m][c][b] (2 MB) ----------------
__global__ __launch_bounds__(256) void build_table(const float* __restrict__ q,
                                                   const float* __restrict__ cw,
                                                   float* __restrict__ table) {
    int tid = blockIdx.x * 256 + threadIdx.x;      // 524288
    int b = tid & 31;
    int c = (tid >> 5) & 255;
    int m = tid >> 13;
    const float* qp = q + b * (MSUB * 4) + m * 4;
    const float* cp = cw + (m * KSUB + c) * 4;
    float s = 0.f;
#pragma unroll
    for (int d = 0; d < 4; ++d) { float t = qp[d] - cp[d]; s += t * t; }
    table[tid] = s;
}

// ---------------- K1b: per-(m,b) min + global per-b max range ----------------
__global__ __launch_bounds__(256) void minmax_kernel(const float* __restrict__ table,
                                                     float* __restrict__ off,
                                                     unsigned* __restrict__ maxr) {
    int m = blockIdx.x >> 5, b = blockIdx.x & 31;
    int c = threadIdx.x;
    float v = table[(m * 256 + c) * 32 + b];
    __shared__ float smin[256], smax[256];
    smin[c] = v; smax[c] = v;
    __syncthreads();
    for (int s = 128; s > 0; s >>= 1) {
        if (c < s) {
            smin[c] = fminf(smin[c], smin[c + s]);
            smax[c] = fmaxf(smax[c], smax[c + s]);
        }
        __syncthreads();
    }
    if (c == 0) {
        off[m * 32 + b] = smin[0];
        atomicMax(&maxr[b], __float_as_uint(smax[0] - smin[0]));  // positive: bit-monotone
    }
}

// ---------------- K1c: per-query scale ----------------
__global__ __launch_bounds__(64) void scale_kernel(const unsigned* __restrict__ maxr,
                                                   float* __restrict__ sVal) {
    int b = threadIdx.x;
    if (b >= BQ) return;
    float r = __uint_as_float(maxr[b]);
    if (r < 1e-20f) r = 1e-20f;
    sVal[b] = 254.5f / r;
}

// ---------------- K1d: quantize table to u8, layout qt[m][c][32 query bytes] ----------------
__global__ __launch_bounds__(256) void quantize_table(const float* __restrict__ table,
                                                      const float* __restrict__ off,
                                                      const float* __restrict__ sVal,
                                                      uint4* __restrict__ qt) {
    int m = blockIdx.x, c = threadIdx.x;
    const float* t = table + (m * 256 + c) * 32;
    unsigned q[32];
#pragma unroll
    for (int b = 0; b < 32; ++b) {
        float x = floorf((t[b] - off[m * 32 + b]) * sVal[b]);
        int qi = (int)x;
        if (qi < 0) qi = 0;
        if (qi > 255) qi = 255;
        q[b] = (unsigned)qi;
    }
    unsigned w[8];
#pragma unroll
    for (int i = 0; i < 8; ++i)
        w[i] = q[4*i] | (q[4*i+1] << 8) | (q[4*i+2] << 16) | (q[4*i+3] << 24);
    uint4 A = {w[0], w[1], w[2], w[3]};
    uint4 B = {w[4], w[5], w[6], w[7]};
    qt[(m * 256 + c) * 2]     = A;     // column m contiguous: 8KB per m
    qt[(m * 256 + c) * 2 + 1] = B;
}

// ---------------- K2a: quantized sums for sampled rows ----------------
__global__ __launch_bounds__(256) void sample_qdists(const char* __restrict__ qtb,
                                                     const int* __restrict__ codes,
                                                     unsigned short* __restrict__ qsamp,
                                                     int stride, int offset) {
    int t = blockIdx.x * 256 + threadIdx.x;        // NSAMP*2 threads
    int j = t >> 1, h = t & 1;
    int n = j * stride + offset;
    const int* crow = codes + (long)n * MSUB;
    const char* tb = qtb + h * 16;
    unsigned AL0 = 0, AH0 = 0, AL1 = 0, AH1 = 0, AL2 = 0, AH2 = 0, AL3 = 0, AH3 = 0;
    for (int m = 0; m < MSUB; ++m) {
        int c = crow[m];
        uint4 v = *(const uint4*)(tb + (size_t)(m * 256 + c) * 32);
        acc8(v.x, AL0, AH0); acc8(v.y, AL1, AH1);
        acc8(v.z, AL2, AH2); acc8(v.w, AL3, AH3);
    }
    unsigned als[4] = {AL0, AL1, AL2, AL3};
    unsigned ahs[4] = {AH0, AH1, AH2, AH3};
#pragma unroll
    for (int i = 0; i < 4; ++i) {
        int b0 = h * 16 + i * 4;
        qsamp[(b0 + 0) * NSAMP + j] = (unsigned short)(als[i] & 0xFFFFu);
        qsamp[(b0 + 1) * NSAMP + j] = (unsigned short)(ahs[i] & 0xFFFFu);
        qsamp[(b0 + 2) * NSAMP + j] = (unsigned short)(als[i] >> 16);
        qsamp[(b0 + 3) * NSAMP + j] = (unsigned short)(ahs[i] >> 16);
    }
}

// ---------------- K2b: 12th-smallest qsum per query via 2-level histogram ----------------
__global__ __launch_bounds__(256) void qtau_kernel(const unsigned short* __restrict__ qsamp,
                                                   unsigned* __restrict__ Qtau) {
    __shared__ int hist[256];
    __shared__ int csel, cbefore;
    int b = blockIdx.x, t = threadIdx.x;
    const unsigned short* q = qsamp + b * NSAMP;
    hist[t] = 0;
    __syncthreads();
    for (int i = t; i < NSAMP; i += 256) atomicAdd(&hist[q[i] >> 6], 1);
    __syncthreads();
    if (t == 0) {
        int c = 0, k = 0;
        for (; k < 255; ++k) { if (c + hist[k] >= TAU_RANK) break; c += hist[k]; }
        csel = k; cbefore = c;
    }
    __syncthreads();
    int sel = csel, before = cbefore;
    __syncthreads();
    hist[t] = 0;
    __syncthreads();
    for (int i = t; i < NSAMP; i += 256) {
        unsigned v = q[i];
        if ((int)(v >> 6) == sel) atomicAdd(&hist[v & 63], 1);
    }
    __syncthreads();
    if (t == 0) {
        int c = before, l = 0;
        for (; l < 63; ++l) { c += hist[l]; if (c >= TAU_RANK) break; }
        if (c < TAU_RANK) l = 63;
        unsigned q12 = ((unsigned)sel << 6) | (unsigned)l;
        unsigned Q = q12 + 65;                     // +64 floor-slack, +1 strict-less
        if (Q > 32767u) Q = 32767u;
        Qtau[b] = Q;
    }
}

// ---------------- K3: coarse scan, m-outer with LDS-resident column ----------------
// 256 threads <-> 512 rows: thread t = (h = t&1, rbase = t>>1), rows rbase + j*128.
__global__ __launch_bounds__(256, 3) void coarse_scan(const uint4* __restrict__ qt4,
                                                      const int4* __restrict__ codes4,
                                                      const unsigned* __restrict__ Qtau,
                                                      int* __restrict__ cnt,
                                                      int* __restrict__ cidx,
                                                      int N) {
    __shared__ unsigned scodes[ROWS * 17];         // 34,816 B (pad 17: conflict-free)
    __shared__ unsigned char cbuf[2][8192];        // 16,384 B column double buffer
    int t = threadIdx.x;
    long tile0 = (long)blockIdx.x * ROWS;

    // stage codes: 512 rows x 16 words, packed u8, coalesced
#pragma unroll
    for (int i = 0; i < 32; ++i) {
        int chunk = i * 256 + t;
        long g = tile0 * 16 + chunk;
        unsigned w = 0;
        if (g < (long)N * 16) w = pack4(codes4[g]);
        scodes[(chunk >> 4) * 17 + (chunk & 15)] = w;
    }
    // prologue: column 0 -> cbuf[0]; column 1 -> regs
    uint4 s0 = qt4[t * 2], s1 = qt4[t * 2 + 1];
    ((uint4*)cbuf[0])[t * 2] = s0;
    ((uint4*)cbuf[0])[t * 2 + 1] = s1;
    s0 = qt4[512 + t * 2]; s1 = qt4[512 + t * 2 + 1];
    __syncthreads();

    int h = t & 1, rbase = t >> 1;
    // thresholds packed
    unsigned TL0, TL1, TL2, TL3, TH0, TH1, TH2, TH3;
    {
        int b0 = h * 16;
        TL0 = Qtau[b0+0]  | (Qtau[b0+2]  << 16); TH0 = Qtau[b0+1]  | (Qtau[b0+3]  << 16);
        TL1 = Qtau[b0+4]  | (Qtau[b0+6]  << 16); TH1 = Qtau[b0+5]  | (Qtau[b0+7]  << 16);
        TL2 = Qtau[b0+8]  | (Qtau[b0+10] << 16); TH2 = Qtau[b0+9]  | (Qtau[b0+11] << 16);
        TL3 = Qtau[b0+12] | (Qtau[b0+14] << 16); TH3 = Qtau[b0+13] | (Qtau[b0+15] << 16);
    }

    unsigned A[4][8];
#pragma unroll
    for (int j = 0; j < 4; ++j)
#pragma unroll
        for (int k = 0; k < 8; ++k) A[j][k] = 0;

    unsigned cw0 = 0, cw1 = 0, cw2 = 0, cw3 = 0;
#pragma unroll 4
    for (int m = 0; m < 64; ++m) {
        if ((m & 3) == 0) {
            int wofs = m >> 2;
            cw0 = scodes[(rbase +   0) * 17 + wofs];
            cw1 = scodes[(rbase + 128) * 17 + wofs];
            cw2 = scodes[(rbase + 256) * 17 + wofs];
            cw3 = scodes[(rbase + 384) * 17 + wofs];
        }
        int sh = (m & 3) * 8;
        const unsigned char* cb = cbuf[m & 1];
        {
            unsigned c = (cw0 >> sh) & 255u;
            uint4 v = *(const uint4*)(cb + c * 32 + h * 16);
            acc8(v.x, A[0][0], A[0][1]); acc8(v.y, A[0][2], A[0][3]);
            acc8(v.z, A[0][4], A[0][5]); acc8(v.w, A[0][6], A[0][7]);
        }
        {
            unsigned c = (cw1 >> sh) & 255u;
            uint4 v = *(const uint4*)(cb + c * 32 + h * 16);
            acc8(v.x, A[1][0], A[1][1]); acc8(v.y, A[1][2], A[1][3]);
            acc8(v.z, A[1][4], A[1][5]); acc8(v.w, A[1][6], A[1][7]);
        }
        {
            unsigned c = (cw2 >> sh) & 255u;
            uint4 v = *(const uint4*)(cb + c * 32 + h * 16);
            acc8(v.x, A[2][0], A[2][1]); acc8(v.y, A[2][2], A[2][3]);
            acc8(v.z, A[2][4], A[2][5]); acc8(v.w, A[2][6], A[2][7]);
        }
        {
            unsigned c = (cw3 >> sh) & 255u;
            uint4 v = *(const uint4*)(cb + c * 32 + h * 16);
            acc8(v.x, A[3][0], A[3][1]); acc8(v.y, A[3][2], A[3][3]);
            acc8(v.z, A[3][4], A[3][5]); acc8(v.w, A[3][6], A[3][7]);
        }
        __syncthreads();                           // all done reading cbuf[(m+1)&1]'s old data
        if (m < 63) {
            uint4* dst = (uint4*)cbuf[(m + 1) & 1];
            dst[t * 2] = s0;                       // column m+1 (loaded 1 iter ago)
            dst[t * 2 + 1] = s1;
            if (m < 62) {                          // issue column m+2 loads
                s0 = qt4[(size_t)(m + 2) * 512 + t * 2];
                s1 = qt4[(size_t)(m + 2) * 512 + t * 2 + 1];
            }
        }
        __syncthreads();                           // column m+1 visible to all
    }

    // compare + append, per row
#pragma unroll
    for (int j = 0; j < 4; ++j) {
        long n = tile0 + rbase + (long)j * 128;
        if (n >= N) continue;
        unsigned s = 0;
        s |= ~((A[j][0] | 0x80008000u) - TL0);
        s |= ~((A[j][1] | 0x80008000u) - TH0);
        s |= ~((A[j][2] | 0x80008000u) - TL1);
        s |= ~((A[j][3] | 0x80008000u) - TH1);
        s |= ~((A[j][4] | 0x80008000u) - TL2);
        s |= ~((A[j][5] | 0x80008000u) - TH2);
        s |= ~((A[j][6] | 0x80008000u) - TL3);
        s |= ~((A[j][7] | 0x80008000u) - TH3);
        if (s & 0x80008000u) {
            unsigned tls[4] = {TL0, TL1, TL2, TL3};
            unsigned ths[4] = {TH0, TH1, TH2, TH3};
#pragma unroll
            for (int i = 0; i < 4; ++i) {
                int b0 = h * 16 + i * 4;
                unsigned al = A[j][2 * i], ah = A[j][2 * i + 1];
                unsigned tl = tls[i], th = ths[i];
                if ((al & 0xFFFFu) < (tl & 0xFFFFu)) {
                    int pos = atomicAdd(&cnt[b0 + 0], 1);
                    if (pos < CAP) cidx[(b0 + 0) * CAP + pos] = (int)n;
                }
                if ((ah & 0xFFFFu) < (th & 0xFFFFu)) {
                    int pos = atomicAdd(&cnt[b0 + 1], 1);
                    if (pos < CAP) cidx[(b0 + 1) * CAP + pos] = (int)n;
                }
                if ((al >> 16) < (tl >> 16)) {
                    int pos = atomicAdd(&cnt[b0 + 2], 1);
                    if (pos < CAP) cidx[(b0 + 2) * CAP + pos] = (int)n;
                }
                if ((ah >> 16) < (th >> 16)) {
                    int pos = atomicAdd(&cnt[b0 + 3], 1);
                    if (pos < CAP) cidx[(b0 + 3) * CAP + pos] = (int)n;
                }
            }
        }
    }
}

// ---------------- K4: exact refine (reference summation order, bit-identical) ----------------
__global__ __launch_bounds__(256) void refine(const float* __restrict__ table,
                                              const int* __restrict__ codes,
                                              const int* __restrict__ cnt,
                                              const int* __restrict__ cidx,
                                              float* __restrict__ cdist) {
    int b = blockIdx.y;
    int pos = blockIdx.x * 256 + threadIdx.x;
    int mc = cnt[b]; if (mc > CAP) mc = CAP;
    if (pos >= mc) return;
    int n = cidx[b * CAP + pos];
    const int4* cr = (const int4*)(codes + (long)n * MSUB);
    const float* tb = table + b;
    float s = 0.f;
#pragma unroll
    for (int w = 0; w < 16; w += 2) {
        int4 ca = cr[w], cb = cr[w + 1];
        float v0 = tb[(size_t)((w * 4 + 0) * 256 + ca.x) * 32];
        float v1 = tb[(size_t)((w * 4 + 1) * 256 + ca.y) * 32];
        float v2 = tb[(size_t)((w * 4 + 2) * 256 + ca.z) * 32];
        float v3 = tb[(size_t)((w * 4 + 3) * 256 + ca.w) * 32];
        float v4 = tb[(size_t)((w * 4 + 4) * 256 + cb.x) * 32];
        float v5 = tb[(size_t)((w * 4 + 5) * 256 + cb.y) * 32];
        float v6 = tb[(size_t)((w * 4 + 6) * 256 + cb.z) * 32];
        float v7 = tb[(size_t)((w * 4 + 7) * 256 + cb.w) * 32];
        s += v0; s += v1; s += v2; s += v3;        // sequential m order: bit-exact
        s += v4; s += v5; s += v6; s += v7;
    }
    cdist[b * CAP + pos] = s;
}

// ---------------- K5: per-query exact top-k via bitonic sort (R1-proven) ----------------
__global__ __launch_bounds__(512) void final_topk(const int* __restrict__ cnt,
                                                  const int* __restrict__ cidx,
                                                  const float* __restrict__ cdist,
                                                  float* __restrict__ out) {
    __shared__ unsigned long long keys[NSORT];     // 64 KB
    int b = blockIdx.x;
    int m = cnt[b];
    if (m > NSORT) m = NSORT;
    for (int i = threadIdx.x; i < NSORT; i += 512) {
        unsigned long long k;
        if (i < m)
            k = ((unsigned long long)__float_as_uint(cdist[b * CAP + i]) << 32) |
                (unsigned)cidx[b * CAP + i];
        else
            k = ~0ULL;
        keys[i] = k;
    }
    __syncthreads();
    for (int kk = 2; kk <= NSORT; kk <<= 1) {
        for (int j = kk >> 1; j > 0; j >>= 1) {
            for (int i = threadIdx.x; i < NSORT; i += 512) {
                int ixj = i ^ j;
                if (ixj > i) {
                    unsigned long long a = keys[i], c = keys[ixj];
                    bool up = ((i & kk) == 0);
                    if ((a > c) == up) { keys[i] = c; keys[ixj] = a; }
                }
            }
            __syncthreads();
        }
    }
    for (int r = threadIdx.x; r < KOUT; r += 512) {
        unsigned long long k = keys[r];
        out[b * KOUT + r] = __uint_as_float((unsigned)(k >> 32));
        out[BQ * KOUT + b * KOUT + r] = (float)(unsigned)(k & 0xFFFFFFFFu);
    }
}

extern "C" void kernel_launch(void* const* d_in, const int* in_sizes, int n_in,
                              void* d_out, int out_size, void* d_ws, size_t ws_size,
                              hipStream_t stream) {
    const float* querys    = (const float*)d_in[0];
    const float* codewords = (const float*)d_in[1];
    const int*   codes     = (const int*)d_in[2];
    float* out = (float*)d_out;
    int N = in_sizes[2] / MSUB;                    // 1,000,000

    char* ws = (char*)d_ws;
    float*          table = (float*)(ws);                        // [0, 2 MB)
    unsigned short* qsamp = (unsigned short*)(ws + (2u << 20));  // [2, 2.5 MB)
    char*           small = ws + (3u << 20);
    float*    sVal  = (float*)(small + 0);                       // 128 B
    unsigned* Qtau  = (unsigned*)(small + 128);                  // 128 B
    int*      cnt   = (int*)(small + 512);                       // 128 B
    unsigned* maxr  = (unsigned*)(small + 640);                  // 128 B
    float*    off   = (float*)(small + 1024);                    // 8 KB
    char*     qtb   = small + 16384;                             // 512 KB u8 table
    int*      cidx  = (int*)(ws + (4u << 20));                   // [4, 5 MB)
    float*    cdist = (float*)(ws + (5u << 20));                 // [5, 6 MB)

    hipMemsetAsync(small + 512, 0, 256, stream);   // cnt + maxr

    build_table<<<(MSUB * KSUB * BQ) / 256, 256, 0, stream>>>(querys, codewords, table);
    minmax_kernel<<<MSUB * BQ, 256, 0, stream>>>(table, off, maxr);
    scale_kernel<<<1, 64, 0, stream>>>(maxr, sVal);
    quantize_table<<<MSUB, 256, 0, stream>>>(table, off, sVal, (uint4*)qtb);

    int stride = N / NSAMP;                        // 122
    int offset = 17;                               // max n = 8191*122+17 < N
    sample_qdists<<<NSAMP * 2 / 256, 256, 0, stream>>>(qtb, codes, qsamp, stride, offset);
    qtau_kernel<<<BQ, 256, 0, stream>>>(qsamp, Qtau);

    int tiles = (N + ROWS - 1) / ROWS;             // 1954
    coarse_scan<<<tiles, 256, 0, stream>>>((const uint4*)qtb, (const int4*)codes,
                                           Qtau, cnt, cidx, N);

    dim3 rgrid(CAP / 256, BQ);
    refine<<<rgrid, 256, 0, stream>>>(table, codes, cnt, cidx, cdist);

    final_topk<<<BQ, 512, 0, stream>>>(cnt, cidx, cdist, out);
}

// Round 7
// 1077.831 us; speedup vs baseline: 1.0663x; 1.0663x over previous
//
#include <hip/hip_runtime.h>
#include <cstdint>

// PQ ADC search, MI355X round 7.
// Coarse scan m-outer with LDS column streaming; column layout [d][c] so every
// random gather is a 4B ds_read_b32 with bank = c&31 (~2-way aliasing = free),
// 8 quads read via one address reg + offset immediates. Quantized-domain tau
// (R6-proven), exact fp32 refine (reference summation order, bit-identical),
// bitonic top-64.

#define BQ 32
#define MSUB 64
#define KSUB 256
#define KOUT 64
#define NSAMP 8192
#define TAU_RANK 12        // 12th smallest sampled qsum; P(miss top-64) ~ 1e-13
#define CAP 8192
#define NSORT 8192
#define ROWS 256           // rows per coarse block (1 per thread)

__device__ __forceinline__ unsigned pack4(int4 a) {
    return (unsigned)(a.x & 255) | ((unsigned)(a.y & 255) << 8) |
           ((unsigned)(a.z & 255) << 16) | ((unsigned)(a.w & 255) << 24);
}

// packed-u16 accumulate: aL += (b0, b2), aH += (b1, b3)
__device__ __forceinline__ void acc8(unsigned v, unsigned& aL, unsigned& aH) {
#if defined(__has_builtin) && __has_builtin(__builtin_amdgcn_perm)
    aL += __builtin_amdgcn_perm(0u, v, 0x0C020C00u);
    aH += __builtin_amdgcn_perm(0u, v, 0x0C030C01u);
#else
    aL += v & 0x00FF00FFu;
    aH += (v >> 8) & 0x00FF00FFu;
#endif
}

// ---------------- K1: fp32 distance table, layout table[m][c][b] (2 MB) ----------------
__global__ __launch_bounds__(256) void build_table(const float* __restrict__ q,
                                                   const float* __restrict__ cw,
                                                   float* __restrict__ table) {
    int tid = blockIdx.x * 256 + threadIdx.x;      // 524288
    int b = tid & 31;
    int c = (tid >> 5) & 255;
    int m = tid >> 13;
    const float* qp = q + b * (MSUB * 4) + m * 4;
    const float* cp = cw + (m * KSUB + c) * 4;
    float s = 0.f;
#pragma unroll
    for (int d = 0; d < 4; ++d) { float t = qp[d] - cp[d]; s += t * t; }
    table[tid] = s;
}

// ---------------- K1b: per-(m,b) min + global per-b max range ----------------
__global__ __launch_bounds__(256) void minmax_kernel(const float* __restrict__ table,
                                                     float* __restrict__ off,
                                                     unsigned* __restrict__ maxr) {
    int m = blockIdx.x >> 5, b = blockIdx.x & 31;
    int c = threadIdx.x;
    float v = table[(m * 256 + c) * 32 + b];
    __shared__ float smin[256], smax[256];
    smin[c] = v; smax[c] = v;
    __syncthreads();
    for (int s = 128; s > 0; s >>= 1) {
        if (c < s) {
            smin[c] = fminf(smin[c], smin[c + s]);
            smax[c] = fmaxf(smax[c], smax[c + s]);
        }
        __syncthreads();
    }
    if (c == 0) {
        off[m * 32 + b] = smin[0];
        atomicMax(&maxr[b], __float_as_uint(smax[0] - smin[0]));  // positive: bit-monotone
    }
}

// ---------------- K1c: per-query scale ----------------
__global__ __launch_bounds__(64) void scale_kernel(const unsigned* __restrict__ maxr,
                                                   float* __restrict__ sVal) {
    int b = threadIdx.x;
    if (b >= BQ) return;
    float r = __uint_as_float(maxr[b]);
    if (r < 1e-20f) r = 1e-20f;
    sVal[b] = 254.5f / r;
}

// ---------------- K1d: quantize table to u8, layout qt[m][d][c] (d = query quad) ----------------
__global__ __launch_bounds__(256) void quantize_table(const float* __restrict__ table,
                                                      const float* __restrict__ off,
                                                      const float* __restrict__ sVal,
                                                      unsigned* __restrict__ qt) {
    int m = blockIdx.x, c = threadIdx.x;
    const float* t = table + (m * 256 + c) * 32;
    unsigned q[32];
#pragma unroll
    for (int b = 0; b < 32; ++b) {
        float x = floorf((t[b] - off[m * 32 + b]) * sVal[b]);
        int qi = (int)x;
        if (qi < 0) qi = 0;
        if (qi > 255) qi = 255;
        q[b] = (unsigned)qi;
    }
#pragma unroll
    for (int d = 0; d < 8; ++d) {
        unsigned w = q[4*d] | (q[4*d+1] << 8) | (q[4*d+2] << 16) | (q[4*d+3] << 24);
        qt[m * 2048 + d * 256 + c] = w;            // column m = 8 KB contiguous
    }
}

// ---------------- K2a: quantized sums for sampled rows (8 lanes/sample) ----------------
__global__ __launch_bounds__(256) void sample_qdists(const unsigned* __restrict__ qt,
                                                     const int* __restrict__ codes,
                                                     unsigned short* __restrict__ qsamp,
                                                     int stride, int offset) {
    int t = blockIdx.x * 256 + threadIdx.x;        // NSAMP*8 threads
    int j = t >> 3, d = t & 7;
    int n = j * stride + offset;
    const int* crow = codes + (long)n * MSUB;
    unsigned AL = 0, AH = 0;
#pragma unroll 8
    for (int m = 0; m < MSUB; ++m) {
        unsigned c = (unsigned)crow[m];
        unsigned v = qt[m * 2048 + d * 256 + c];
        acc8(v, AL, AH);
    }
    int b0 = d * 4;
    qsamp[(b0 + 0) * NSAMP + j] = (unsigned short)(AL & 0xFFFFu);
    qsamp[(b0 + 1) * NSAMP + j] = (unsigned short)(AH & 0xFFFFu);
    qsamp[(b0 + 2) * NSAMP + j] = (unsigned short)(AL >> 16);
    qsamp[(b0 + 3) * NSAMP + j] = (unsigned short)(AH >> 16);
}

// ---------------- K2b: 12th-smallest qsum per query via 2-level histogram ----------------
__global__ __launch_bounds__(256) void qtau_kernel(const unsigned short* __restrict__ qsamp,
                                                   unsigned* __restrict__ Qtau) {
    __shared__ int hist[256];
    __shared__ int csel, cbefore;
    int b = blockIdx.x, t = threadIdx.x;
    const unsigned short* q = qsamp + b * NSAMP;
    hist[t] = 0;
    __syncthreads();
    for (int i = t; i < NSAMP; i += 256) atomicAdd(&hist[q[i] >> 6], 1);
    __syncthreads();
    if (t == 0) {
        int c = 0, k = 0;
        for (; k < 255; ++k) { if (c + hist[k] >= TAU_RANK) break; c += hist[k]; }
        csel = k; cbefore = c;
    }
    __syncthreads();
    int sel = csel, before = cbefore;
    __syncthreads();
    hist[t] = 0;
    __syncthreads();
    for (int i = t; i < NSAMP; i += 256) {
        unsigned v = q[i];
        if ((int)(v >> 6) == sel) atomicAdd(&hist[v & 63], 1);
    }
    __syncthreads();
    if (t == 0) {
        int c = before, l = 0;
        for (; l < 63; ++l) { c += hist[l]; if (c >= TAU_RANK) break; }
        if (c < TAU_RANK) l = 63;
        unsigned q12 = ((unsigned)sel << 6) | (unsigned)l;
        unsigned Q = q12 + 65;                     // +64 floor-slack, +1 strict-less
        if (Q > 32767u) Q = 32767u;
        Qtau[b] = Q;
    }
}

// ---------------- K3: coarse scan, m-outer; LDS column [d][c], 4B gathers ----------------
__global__ __launch_bounds__(256, 4) void coarse_scan(const uint4* __restrict__ qt4,
                                                      const int4* __restrict__ codes4,
                                                      const unsigned* __restrict__ Qtau,
                                                      int* __restrict__ cnt,
                                                      int* __restrict__ cidx,
                                                      int N) {
    __shared__ unsigned scodes[ROWS * 17];         // 17,408 B (pad: conflict-free)
    __shared__ unsigned char cbuf[2][8192];        // 16,384 B column double buffer
    int t = threadIdx.x;
    long tile0 = (long)blockIdx.x * ROWS;

    // stage codes: 256 rows x 16 packed dwords, coalesced
#pragma unroll
    for (int i = 0; i < 16; ++i) {
        int chunk = i * 256 + t;                   // row = chunk>>4, w = chunk&15
        long g = tile0 * 16 + chunk;
        unsigned w = 0;
        if (g < (long)N * 16) w = pack4(codes4[g]);
        scodes[(chunk >> 4) * 17 + (chunk & 15)] = w;
    }
    // prologue: column 0 -> cbuf[0]; column 1 -> regs
    uint4 s0 = qt4[t * 2], s1 = qt4[t * 2 + 1];
    ((uint4*)cbuf[0])[t * 2] = s0;
    ((uint4*)cbuf[0])[t * 2 + 1] = s1;
    s0 = qt4[512 + t * 2]; s1 = qt4[512 + t * 2 + 1];
    __syncthreads();

    unsigned A[16];
#pragma unroll
    for (int k = 0; k < 16; ++k) A[k] = 0;

    unsigned cw = 0;
#pragma unroll 4
    for (int m = 0; m < 64; ++m) {
        if ((m & 3) == 0) cw = scodes[t * 17 + (m >> 2)];
        unsigned c = (cw >> ((m & 3) * 8)) & 255u;
        const unsigned* p = (const unsigned*)(cbuf[m & 1] + c * 4);
#pragma unroll
        for (int d = 0; d < 8; ++d) {
            unsigned v = p[d * 256];               // ds_read_b32 offset:d*1024
            acc8(v, A[2 * d], A[2 * d + 1]);
        }
        __syncthreads();                           // all reads of cbuf[(m+1)&1] old data done
        if (m < 63) {
            uint4* dst = (uint4*)cbuf[(m + 1) & 1];
            dst[t * 2] = s0;                       // column m+1 (fetched 1 iter ago)
            dst[t * 2 + 1] = s1;
            if (m < 62) {
                s0 = qt4[(size_t)(m + 2) * 512 + t * 2];
                s1 = qt4[(size_t)(m + 2) * 512 + t * 2 + 1];
            }
        }
        __syncthreads();                           // column m+1 visible
    }

    long n = tile0 + t;
    if (n >= N) return;
    unsigned sbits = 0;
    unsigned TL[8], TH[8];
#pragma unroll
    for (int d = 0; d < 8; ++d) {
        TL[d] = Qtau[4 * d] | (Qtau[4 * d + 2] << 16);
        TH[d] = Qtau[4 * d + 1] | (Qtau[4 * d + 3] << 16);
        sbits |= ~((A[2 * d] | 0x80008000u) - TL[d]);
        sbits |= ~((A[2 * d + 1] | 0x80008000u) - TH[d]);
    }
    if (sbits & 0x80008000u) {
#pragma unroll
        for (int d = 0; d < 8; ++d) {
            unsigned al = A[2 * d], ah = A[2 * d + 1], tl = TL[d], th = TH[d];
            int b0 = d * 4;
            if ((al & 0xFFFFu) < (tl & 0xFFFFu)) {
                int pos = atomicAdd(&cnt[b0 + 0], 1);
                if (pos < CAP) cidx[(b0 + 0) * CAP + pos] = (int)n;
            }
            if ((ah & 0xFFFFu) < (th & 0xFFFFu)) {
                int pos = atomicAdd(&cnt[b0 + 1], 1);
                if (pos < CAP) cidx[(b0 + 1) * CAP + pos] = (int)n;
            }
            if ((al >> 16) < (tl >> 16)) {
                int pos = atomicAdd(&cnt[b0 + 2], 1);
                if (pos < CAP) cidx[(b0 + 2) * CAP + pos] = (int)n;
            }
            if ((ah >> 16) < (th >> 16)) {
                int pos = atomicAdd(&cnt[b0 + 3], 1);
                if (pos < CAP) cidx[(b0 + 3) * CAP + pos] = (int)n;
            }
        }
    }
}

// ---------------- K4: exact refine (reference summation order, bit-identical) ----------------
__global__ __launch_bounds__(256) void refine(const float* __restrict__ table,
                                              const int* __restrict__ codes,
                                              const int* __restrict__ cnt,
                                              const int* __restrict__ cidx,
                                              float* __restrict__ cdist) {
    int b = blockIdx.y;
    int pos = blockIdx.x * 256 + threadIdx.x;
    int mc = cnt[b]; if (mc > CAP) mc = CAP;
    if (pos >= mc) return;
    int n = cidx[b * CAP + pos];
    const int4* cr = (const int4*)(codes + (long)n * MSUB);
    const float* tb = table + b;
    float s = 0.f;
#pragma unroll
    for (int w = 0; w < 16; w += 2) {
        int4 ca = cr[w], cb = cr[w + 1];
        float v0 = tb[(size_t)((w * 4 + 0) * 256 + ca.x) * 32];
        float v1 = tb[(size_t)((w * 4 + 1) * 256 + ca.y) * 32];
        float v2 = tb[(size_t)((w * 4 + 2) * 256 + ca.z) * 32];
        float v3 = tb[(size_t)((w * 4 + 3) * 256 + ca.w) * 32];
        float v4 = tb[(size_t)((w * 4 + 4) * 256 + cb.x) * 32];
        float v5 = tb[(size_t)((w * 4 + 5) * 256 + cb.y) * 32];
        float v6 = tb[(size_t)((w * 4 + 6) * 256 + cb.z) * 32];
        float v7 = tb[(size_t)((w * 4 + 7) * 256 + cb.w) * 32];
        s += v0; s += v1; s += v2; s += v3;        // sequential m order: bit-exact
        s += v4; s += v5; s += v6; s += v7;
    }
    cdist[b * CAP + pos] = s;
}

// ---------------- K5: per-query exact top-k via bitonic sort ----------------
__global__ __launch_bounds__(512) void final_topk(const int* __restrict__ cnt,
                                                  const int* __restrict__ cidx,
                                                  const float* __restrict__ cdist,
                                                  float* __restrict__ out) {
    __shared__ unsigned long long keys[NSORT];     // 64 KB
    int b = blockIdx.x;
    int m = cnt[b];
    if (m > NSORT) m = NSORT;
    for (int i = threadIdx.x; i < NSORT; i += 512) {
        unsigned long long k;
        if (i < m)
            k = ((unsigned long long)__float_as_uint(cdist[b * CAP + i]) << 32) |
                (unsigned)cidx[b * CAP + i];
        else
            k = ~0ULL;
        keys[i] = k;
    }
    __syncthreads();
    for (int kk = 2; kk <= NSORT; kk <<= 1) {
        for (int j = kk >> 1; j > 0; j >>= 1) {
            for (int i = threadIdx.x; i < NSORT; i += 512) {
                int ixj = i ^ j;
                if (ixj > i) {
                    unsigned long long a = keys[i], c = keys[ixj];
                    bool up = ((i & kk) == 0);
                    if ((a > c) == up) { keys[i] = c; keys[ixj] = a; }
                }
            }
            __syncthreads();
        }
    }
    for (int r = threadIdx.x; r < KOUT; r += 512) {
        unsigned long long k = keys[r];
        out[b * KOUT + r] = __uint_as_float((unsigned)(k >> 32));
        out[BQ * KOUT + b * KOUT + r] = (float)(unsigned)(k & 0xFFFFFFFFu);
    }
}

extern "C" void kernel_launch(void* const* d_in, const int* in_sizes, int n_in,
                              void* d_out, int out_size, void* d_ws, size_t ws_size,
                              hipStream_t stream) {
    const float* querys    = (const float*)d_in[0];
    const float* codewords = (const float*)d_in[1];
    const int*   codes     = (const int*)d_in[2];
    float* out = (float*)d_out;
    int N = in_sizes[2] / MSUB;                    // 1,000,000

    char* ws = (char*)d_ws;
    float*          table = (float*)(ws);                        // [0, 2 MB)
    unsigned short* qsamp = (unsigned short*)(ws + (2u << 20));  // [2, 2.5 MB)
    char*           small = ws + (3u << 20);
    float*    sVal  = (float*)(small + 0);                       // 128 B
    unsigned* Qtau  = (unsigned*)(small + 128);                  // 128 B
    int*      cnt   = (int*)(small + 512);                       // 128 B
    unsigned* maxr  = (unsigned*)(small + 640);                  // 128 B
    float*    off   = (float*)(small + 1024);                    // 8 KB
    unsigned* qt    = (unsigned*)(small + 16384);                // 512 KB u8 table [m][d][c]
    int*      cidx  = (int*)(ws + (4u << 20));                   // [4, 5 MB)
    float*    cdist = (float*)(ws + (5u << 20));                 // [5, 6 MB)

    hipMemsetAsync(small + 512, 0, 256, stream);   // cnt + maxr

    build_table<<<(MSUB * KSUB * BQ) / 256, 256, 0, stream>>>(querys, codewords, table);
    minmax_kernel<<<MSUB * BQ, 256, 0, stream>>>(table, off, maxr);
    scale_kernel<<<1, 64, 0, stream>>>(maxr, sVal);
    quantize_table<<<MSUB, 256, 0, stream>>>(table, off, sVal, qt);

    int stride = N / NSAMP;                        // 122
    int offset = 17;                               // max n = 8191*122+17 < N
    sample_qdists<<<NSAMP * 8 / 256, 256, 0, stream>>>(qt, codes, qsamp, stride, offset);
    qtau_kernel<<<BQ, 256, 0, stream>>>(qsamp, Qtau);

    int tiles = (N + ROWS - 1) / ROWS;             // 3907
    coarse_scan<<<tiles, 256, 0, stream>>>((const uint4*)qt, (const int4*)codes,
                                           Qtau, cnt, cidx, N);

    dim3 rgrid(CAP / 256, BQ);
    refine<<<rgrid, 256, 0, stream>>>(table, codes, cnt, cidx, cdist);

    final_topk<<<BQ, 512, 0, stream>>>(cnt, cidx, cdist, out);
}